// Round 18
// baseline (425.755 us; speedup 1.0000x reference)
//
#include <hip/hip_runtime.h>
#include <math.h>

typedef unsigned short u16;
typedef unsigned int u32;
using bf16x8 = __attribute__((ext_vector_type(8))) short;
using f32x4  = __attribute__((ext_vector_type(4))) float;

#define DD 4096
#define NB 256            // batch
#define SPLIT_K 8
#define PSTRIDE (NB * DD) // elements per partial plane
#define PLANE (NB * DD)   // floats per transform layer plane

__device__ __forceinline__ u16 f2bf(float f) {
  unsigned int u = __float_as_uint(f);
  u += 0x7fffu + ((u >> 16) & 1u);   // RNE
  return (u16)(u >> 16);
}
__device__ __forceinline__ float bf2f(u16 h) {
  return __uint_as_float((u32)h << 16);
}
__device__ __forceinline__ unsigned int pack2bf(float a, float b) {
  return (unsigned int)f2bf(a) | ((unsigned int)f2bf(b) << 16);
}
__device__ __forceinline__ void async_cp16(const u16* g, u16* l) {
  __builtin_amdgcn_global_load_lds(
      (const __attribute__((address_space(1))) unsigned int*)g,
      (__attribute__((address_space(3))) unsigned int*)l, 16, 0, 0);
}
// dot of 8 bf16 pairs packed in uint4 (lo/hi of each dword), f32 accumulate
__device__ __forceinline__ float dot8bf(const uint4 a, const uint4 b) {
  float s;
  s  = __uint_as_float(a.x << 16) * __uint_as_float(b.x << 16);
  s += __uint_as_float(a.x & 0xffff0000u) * __uint_as_float(b.x & 0xffff0000u);
  s += __uint_as_float(a.y << 16) * __uint_as_float(b.y << 16);
  s += __uint_as_float(a.y & 0xffff0000u) * __uint_as_float(b.y & 0xffff0000u);
  s += __uint_as_float(a.z << 16) * __uint_as_float(b.z << 16);
  s += __uint_as_float(a.z & 0xffff0000u) * __uint_as_float(b.z & 0xffff0000u);
  s += __uint_as_float(a.w << 16) * __uint_as_float(b.w << 16);
  s += __uint_as_float(a.w & 0xffff0000u) * __uint_as_float(b.w & 0xffff0000u);
  return s;
}
__device__ __forceinline__ float dot4f(const float4 a, const float4 b) {
  return a.x * b.x + a.y * b.y + a.z * b.z + a.w * b.w;
}

// ---------------------------------------------------------------------------
// GEMM: tile 128x64 (M-split 2), K-chunk 512 (8 iters of BK=64).
// grid (64 nt, 16 = kz*2+mt) = 1024 WGs; 24 KB LDS + <=64 VGPR ((512,8))
// -> 4 WG/CU = 32 waves/CU. TLP hides the per-iter barrier drain.
// ---------------------------------------------------------------------------
__global__ __launch_bounds__(512, 8) void gemm_kernel(
    const u16* __restrict__ A, const float* __restrict__ W,
    u16* __restrict__ part)
{
  const int nt = blockIdx.x;
  const int mt = blockIdx.y & 1;
  const int kz = blockIdx.y >> 1;
  const int t = threadIdx.x;
  const int w = t >> 6, l = t & 63;

  __shared__ __align__(16) u16 As[128 * 64];   // 16 KB
  __shared__ __align__(16) u16 Bs[64 * 64];    // 8 KB

  const int colg0 = nt << 6;
  const int m0 = mt << 7;
  const int k0 = kz << 9;                      // K-chunk of 512

  f32x4 acc[2][2];
#pragma unroll
  for (int mi = 0; mi < 2; ++mi)
#pragma unroll
    for (int nj = 0; nj < 2; ++nj)
      acc[mi][nj] = (f32x4){0.f, 0.f, 0.f, 0.f};

  const int wm = w & 3, wn = w >> 2;
  const int lr = l & 15, lg = l >> 4;
  const int arow_l = (w << 3) + (l >> 3);
  const int acl = l & 7;
  const int bn_l = t >> 3;
  const int bcc = t & 7;

  for (int tt = 0; tt < 8; ++tt) {
    const int kk = k0 + (tt << 6);
    __syncthreads();
#pragma unroll
    for (int r2 = 0; r2 < 2; ++r2) {
      const int row = (r2 << 6) + arow_l;
      const int cs = acl ^ (row & 7);
      async_cp16(A + ((size_t)(m0 + row) << 12) + kk + (cs << 3),
                 &As[(r2 << 12) + (w << 9)]);
    }
    {
      const float* wsrc = W + ((size_t)(colg0 + bn_l) << 12) + kk + (bcc << 3);
      const float4 f0 = *reinterpret_cast<const float4*>(wsrc);
      const float4 f1 = *reinterpret_cast<const float4*>(wsrc + 4);
      uint4 pk;
      pk.x = pack2bf(f0.x, f0.y);
      pk.y = pack2bf(f0.z, f0.w);
      pk.z = pack2bf(f1.x, f1.y);
      pk.w = pack2bf(f1.z, f1.w);
      *reinterpret_cast<uint4*>(&Bs[(bn_l << 6) + ((bcc ^ (bn_l & 7)) << 3)]) = pk;
    }
    __syncthreads();
#pragma unroll
    for (int ks = 0; ks < 2; ++ks) {
      const int cg = (ks << 2) + lg;
      bf16x8 av[2], bv[2];
#pragma unroll
      for (int mi = 0; mi < 2; ++mi) {
        const int fr = (wm << 5) + (mi << 4) + lr;
        av[mi] = *reinterpret_cast<const bf16x8*>(&As[(fr << 6) + ((cg ^ (fr & 7)) << 3)]);
      }
#pragma unroll
      for (int nj = 0; nj < 2; ++nj) {
        const int fc = (wn << 5) + (nj << 4) + lr;
        bv[nj] = *reinterpret_cast<const bf16x8*>(&Bs[(fc << 6) + ((cg ^ (fc & 7)) << 3)]);
      }
#pragma unroll
      for (int mi = 0; mi < 2; ++mi)
#pragma unroll
        for (int nj = 0; nj < 2; ++nj)
          acc[mi][nj] = __builtin_amdgcn_mfma_f32_16x16x32_bf16(
              av[mi], bv[nj], acc[mi][nj], 0, 0, 0);
    }
  }

  u16* pout = part + (size_t)kz * PSTRIDE;
#pragma unroll
  for (int mi = 0; mi < 2; ++mi)
#pragma unroll
    for (int nj = 0; nj < 2; ++nj) {
      const int col = colg0 + (wn << 5) + (nj << 4) + lr;
#pragma unroll
      for (int j = 0; j < 4; ++j) {
        const int row = m0 + (wm << 5) + (mi << 4) + (lg << 2) + j;
        pout[((size_t)row << 12) + col] = f2bf(acc[mi][nj][j]);
      }
    }
}

// ---------------------------------------------------------------------------
// Update v3 (R17 body, 8 partial planes).
// ---------------------------------------------------------------------------
struct UpdSmem {
  float U[64][20], V[64][20], P[64][20];
  u16 UTb[16][72], VTb[16][72], PTb[16][72], QTb[16][72];
  float S[16][16], ST[16][16];
  float sinv[16];
  union {
    struct {
      u16 dYb[64][72];
      u16 dYTb[64][80];
    };
    struct {
      float Fu[64][20], Fv[64][20];
      u16 FuTb[16][72], FvTb[16][72];
      float R[16][20], RT[16][20], RvT[16][20];
      float G1u[16][20], G1v[16][20];
      float G2u[16][20], G2v[16][20];
      float M1uT[16][20], M1vT[16][20];
    };
  };
};

__device__ __forceinline__ void write_xf_tail(
    UpdSmem& m, int t, int b, float* __restrict__ Xf, u16* __restrict__ Xfb,
    float* __restrict__ outL_plane)
{
  const int p = t >> 3;
  const int j0 = (t << 1) & 15;
  {
    const float4* u4 = reinterpret_cast<const float4*>(&m.U[p][0]);
    const float4* sa = reinterpret_cast<const float4*>(&m.ST[j0][0]);
    const float4* sb = reinterpret_cast<const float4*>(&m.ST[j0 + 1][0]);
    float a0 = 0.f, a1 = 0.f;
#pragma unroll
    for (int k4 = 0; k4 < 4; ++k4) {
      const float4 uu = u4[k4];
      a0 += dot4f(uu, sa[k4]);
      a1 += dot4f(uu, sb[k4]);
    }
    m.P[p][j0] = a0; m.P[p][j0 + 1] = a1;
  }
  __syncthreads();
  {
    const int q0 = (t & 7) << 3;
    float4 pr[4];
    const float4* p4 = reinterpret_cast<const float4*>(&m.P[p][0]);
#pragma unroll
    for (int k4 = 0; k4 < 4; ++k4) pr[k4] = p4[k4];
    float res[8];
#pragma unroll
    for (int e = 0; e < 8; ++e) {
      const float4* v4 = reinterpret_cast<const float4*>(&m.V[q0 + e][0]);
      res[e] = dot4f(pr[0], v4[0]) + dot4f(pr[1], v4[1]) +
               dot4f(pr[2], v4[2]) + dot4f(pr[3], v4[3]);
    }
    const size_t ko = ((size_t)b << 12) + (p << 6) + q0;
    float4* xo = reinterpret_cast<float4*>(Xf + ko);
    const float4 r0 = make_float4(res[0], res[1], res[2], res[3]);
    const float4 r1 = make_float4(res[4], res[5], res[6], res[7]);
    xo[0] = r0; xo[1] = r1;
    uint4 pk;
    pk.x = pack2bf(res[0], res[1]); pk.y = pack2bf(res[2], res[3]);
    pk.z = pack2bf(res[4], res[5]); pk.w = pack2bf(res[6], res[7]);
    *reinterpret_cast<uint4*>(Xfb + ko) = pk;
    if (outL_plane != nullptr) {
      float4* op = reinterpret_cast<float4*>(outL_plane + ko);
      op[0] = r0; op[1] = r1;
    }
  }
}

__global__ __launch_bounds__(512) void update_kernel(
    const u16* __restrict__ part, const float* __restrict__ bias,
    float* __restrict__ u_g, float* __restrict__ v_g, float* __restrict__ s_g,
    float* __restrict__ Xf, u16* __restrict__ Xfb,
    float* __restrict__ outL, int layer)
{
  const int b = blockIdx.x, t = threadIdx.x;
  __shared__ __align__(16) UpdSmem m;
  float* outL_plane = outL + (size_t)layer * PLANE;
  const size_t ub = (size_t)b << 10;
  const int p8 = t >> 3;
  const int j0 = (t << 1) & 15;

  // ---- Phase 1: loads + bf16 copies
  {
    const float2 u2 = *reinterpret_cast<const float2*>(u_g + ub + (t << 1));
    const float2 v2 = *reinterpret_cast<const float2*>(v_g + ub + (t << 1));
    const int r = t >> 3, c = (t & 7) << 1;
    m.U[r][c] = u2.x; m.U[r][c + 1] = u2.y;
    m.V[r][c] = v2.x; m.V[r][c + 1] = v2.y;
    m.UTb[c][r] = f2bf(u2.x); m.UTb[c + 1][r] = f2bf(u2.y);
    m.VTb[c][r] = f2bf(v2.x); m.VTb[c + 1][r] = f2bf(v2.y);
    if (t < 256) {
      const float sv = s_g[((size_t)b << 8) + t];
      m.S[t >> 4][t & 15] = sv;
      m.ST[t & 15][t >> 4] = sv;
    }
    if (t < 16) m.sinv[t] = 1.0f / s_g[((size_t)b << 8) + t * 17];
    const u16* p0 = part + ((size_t)b << 12) + (t << 3);
    float x[8];
#pragma unroll
    for (int e = 0; e < 8; ++e) x[e] = 0.f;
#pragma unroll
    for (int kzi = 0; kzi < SPLIT_K; ++kzi) {
      const uint4 v = *reinterpret_cast<const uint4*>(p0 + (size_t)kzi * PSTRIDE);
      x[0] += bf2f((u16)(v.x & 0xffff)); x[1] += bf2f((u16)(v.x >> 16));
      x[2] += bf2f((u16)(v.y & 0xffff)); x[3] += bf2f((u16)(v.y >> 16));
      x[4] += bf2f((u16)(v.z & 0xffff)); x[5] += bf2f((u16)(v.z >> 16));
      x[6] += bf2f((u16)(v.w & 0xffff)); x[7] += bf2f((u16)(v.w >> 16));
    }
    if (bias != nullptr) {
      const float4 b0 = *reinterpret_cast<const float4*>(bias + (t << 3));
      const float4 b1 = *reinterpret_cast<const float4*>(bias + (t << 3) + 4);
      x[0] += b0.x; x[1] += b0.y; x[2] += b0.z; x[3] += b0.w;
      x[4] += b1.x; x[5] += b1.y; x[6] += b1.z; x[7] += b1.w;
    }
#pragma unroll
    for (int e = 0; e < 8; ++e) x[e] = fmaxf(x[e], 0.f);
    const int r2 = t >> 3, c2 = (t & 7) << 3, sw = (t & 7) << 3;
    uint4 pk;
    pk.x = pack2bf(x[0], x[1]); pk.y = pack2bf(x[2], x[3]);
    pk.z = pack2bf(x[4], x[5]); pk.w = pack2bf(x[6], x[7]);
    *reinterpret_cast<uint4*>(&m.dYb[r2][c2]) = pk;
#pragma unroll
    for (int e = 0; e < 8; ++e) m.dYTb[c2 + e][r2 ^ sw] = f2bf(x[e]);
  }
  __syncthreads();

  // ---- Phase 2
  {
    const int tt = t & 255;
    const int p = tt & 63, jg = (tt >> 6) << 2;
    float a[4] = {0.f, 0.f, 0.f, 0.f};
    if (t < 256) {
      const uint4* dy = reinterpret_cast<const uint4*>(&m.dYb[p][0]);
#pragma unroll
      for (int r8 = 0; r8 < 8; ++r8) {
        const uint4 d = dy[r8];
#pragma unroll
        for (int e = 0; e < 4; ++e)
          a[e] += dot8bf(d, reinterpret_cast<const uint4*>(&m.VTb[jg + e][0])[r8]);
      }
#pragma unroll
      for (int e = 0; e < 4; ++e) m.PTb[jg + e][p] = f2bf(a[e]);
    } else {
      const int sw = (p >> 3) & 7;
      const uint4* dy = reinterpret_cast<const uint4*>(&m.dYTb[p][0]);
#pragma unroll
      for (int r8 = 0; r8 < 8; ++r8) {
        const uint4 d = dy[r8 ^ sw];
#pragma unroll
        for (int e = 0; e < 4; ++e)
          a[e] += dot8bf(d, reinterpret_cast<const uint4*>(&m.UTb[jg + e][0])[r8]);
      }
#pragma unroll
      for (int e = 0; e < 4; ++e) m.QTb[jg + e][p] = f2bf(a[e]);
    }
  }
  __syncthreads();

  // ---- Phase 3
  {
    const int tt = t & 255, i = tt >> 4, j = tt & 15;
    if (t < 256) {
      float r0 = 0.f, g0 = 0.f;
#pragma unroll
      for (int r8 = 0; r8 < 8; ++r8) {
        const uint4 ui = reinterpret_cast<const uint4*>(&m.UTb[i][0])[r8];
        r0 += dot8bf(ui, reinterpret_cast<const uint4*>(&m.PTb[j][0])[r8]);
        g0 += dot8bf(ui, reinterpret_cast<const uint4*>(&m.UTb[j][0])[r8]);
      }
      m.R[i][j] = r0; m.RT[j][i] = r0; m.G2u[i][j] = g0;
    } else {
      float r0 = 0.f, g0 = 0.f;
#pragma unroll
      for (int r8 = 0; r8 < 8; ++r8) {
        const uint4 vi = reinterpret_cast<const uint4*>(&m.VTb[i][0])[r8];
        r0 += dot8bf(vi, reinterpret_cast<const uint4*>(&m.QTb[j][0])[r8]);
        g0 += dot8bf(vi, reinterpret_cast<const uint4*>(&m.VTb[j][0])[r8]);
      }
      m.RvT[j][i] = r0; m.G2v[i][j] = g0;
    }
  }
  __syncthreads();

  // ---- Phase 4
  {
    float f0 = bf2f(m.PTb[j0][p8]), f1 = bf2f(m.PTb[j0 + 1][p8]);
    float g0 = bf2f(m.QTb[j0][p8]), g1 = bf2f(m.QTb[j0 + 1][p8]);
    const float4* u4 = reinterpret_cast<const float4*>(&m.U[p8][0]);
    const float4* v4 = reinterpret_cast<const float4*>(&m.V[p8][0]);
    const float4* ra = reinterpret_cast<const float4*>(&m.RT[j0][0]);
    const float4* rb = reinterpret_cast<const float4*>(&m.RT[j0 + 1][0]);
    const float4* rc = reinterpret_cast<const float4*>(&m.RvT[j0][0]);
    const float4* rd = reinterpret_cast<const float4*>(&m.RvT[j0 + 1][0]);
#pragma unroll
    for (int k4 = 0; k4 < 4; ++k4) {
      const float4 uu = u4[k4], vv = v4[k4];
      f0 -= dot4f(uu, ra[k4]);
      f1 -= dot4f(uu, rb[k4]);
      g0 -= dot4f(vv, rc[k4]);
      g1 -= dot4f(vv, rd[k4]);
    }
    const float s0 = m.sinv[j0], s1 = m.sinv[j0 + 1];
    f0 *= s0; f1 *= s1; g0 *= s0; g1 *= s1;
    *reinterpret_cast<float2*>(&m.Fu[p8][j0]) = make_float2(f0, f1);
    *reinterpret_cast<float2*>(&m.Fv[p8][j0]) = make_float2(g0, g1);
    m.FuTb[j0][p8] = f2bf(f0); m.FuTb[j0 + 1][p8] = f2bf(f1);
    m.FvTb[j0][p8] = f2bf(g0); m.FvTb[j0 + 1][p8] = f2bf(g1);
  }
  __syncthreads();

  // ---- Phase 5
  {
    const int tt = t & 255, i = tt >> 4, j = tt & 15;
    if (t < 256) {
      float g = 0.f;
#pragma unroll
      for (int r8 = 0; r8 < 8; ++r8)
        g += dot8bf(reinterpret_cast<const uint4*>(&m.UTb[i][0])[r8],
                    reinterpret_cast<const uint4*>(&m.FuTb[j][0])[r8]);
      m.G1u[i][j] = g;
    } else {
      float g = 0.f;
#pragma unroll
      for (int r8 = 0; r8 < 8; ++r8)
        g += dot8bf(reinterpret_cast<const uint4*>(&m.VTb[i][0])[r8],
                    reinterpret_cast<const uint4*>(&m.FvTb[j][0])[r8]);
      m.G1v[i][j] = g;
    }
  }
  __syncthreads();

  // ---- Phase 6
  {
    const int tt = t & 255, i = tt >> 4, j = tt & 15;
    if (t < 256) {
      float mm = 0.f;
#pragma unroll
      for (int k4 = 0; k4 < 4; ++k4)
        mm += dot4f(reinterpret_cast<const float4*>(&m.G1u[i][0])[k4],
                    reinterpret_cast<const float4*>(&m.G2u[j][0])[k4]);
      m.M1uT[j][i] = mm;
    } else {
      float mm = 0.f;
#pragma unroll
      for (int k4 = 0; k4 < 4; ++k4)
        mm += dot4f(reinterpret_cast<const float4*>(&m.G1v[i][0])[k4],
                    reinterpret_cast<const float4*>(&m.G2v[j][0])[k4]);
      m.M1vT[j][i] = mm;
    }
  }
  __syncthreads();

  // ---- Phase 7
  {
    float du0 = 0.f, du1 = 0.f, dv0 = 0.f, dv1 = 0.f;
    const float4* fu4 = reinterpret_cast<const float4*>(&m.Fu[p8][0]);
    const float4* fv4 = reinterpret_cast<const float4*>(&m.Fv[p8][0]);
    const float4* ma = reinterpret_cast<const float4*>(&m.M1uT[j0][0]);
    const float4* mb = reinterpret_cast<const float4*>(&m.M1uT[j0 + 1][0]);
    const float4* mc = reinterpret_cast<const float4*>(&m.M1vT[j0][0]);
    const float4* md = reinterpret_cast<const float4*>(&m.M1vT[j0 + 1][0]);
#pragma unroll
    for (int k4 = 0; k4 < 4; ++k4) {
      const float4 fu = fu4[k4], fv = fv4[k4];
      du0 += dot4f(fu, ma[k4]);
      du1 += dot4f(fu, mb[k4]);
      dv0 += dot4f(fv, mc[k4]);
      dv1 += dot4f(fv, md[k4]);
    }
    const float nu0 = m.U[p8][j0]     - 1e-6f * du0;
    const float nu1 = m.U[p8][j0 + 1] - 1e-6f * du1;
    const float nv0 = m.V[p8][j0]     - 1e-6f * dv0;
    const float nv1 = m.V[p8][j0 + 1] - 1e-6f * dv1;
    float ns = 0.f;
    if (t < 256) ns = m.S[t >> 4][t & 15] + 1e-3f * m.R[t >> 4][t & 15];
    __syncthreads();
    m.U[p8][j0] = nu0; m.U[p8][j0 + 1] = nu1;
    m.V[p8][j0] = nv0; m.V[p8][j0 + 1] = nv1;
    *reinterpret_cast<float2*>(u_g + ub + (p8 << 4) + j0) = make_float2(nu0, nu1);
    *reinterpret_cast<float2*>(v_g + ub + (p8 << 4) + j0) = make_float2(nv0, nv1);
    if (t < 256) {
      m.S[t >> 4][t & 15] = ns;
      m.ST[t & 15][t >> 4] = ns;
      s_g[((size_t)b << 8) + t] = ns;
    }
  }
  __syncthreads();

  write_xf_tail(m, t, b, Xf, Xfb, outL_plane);
}

// ---------------------------------------------------------------------------
// Init: unpack u, s, v; Xf0 = u s v^T.
// ---------------------------------------------------------------------------
__global__ __launch_bounds__(512) void init_kernel(
    const float* __restrict__ X, float* __restrict__ u_g, float* __restrict__ v_g,
    float* __restrict__ s_g, float* __restrict__ Xf, u16* __restrict__ Xfb)
{
  const int b = blockIdx.x, t = threadIdx.x;
  __shared__ __align__(16) UpdSmem m;
  const float* xb = X + (size_t)b * 3072;
  const size_t ub = (size_t)b << 10;
  {
    const float2 u2 = *reinterpret_cast<const float2*>(xb + (t << 1));
    const int r = t >> 3, c = (t & 7) << 1;
    m.U[r][c] = u2.x; m.U[r][c + 1] = u2.y;
    *reinterpret_cast<float2*>(u_g + ub + (t << 1)) = u2;
    if (t < 256) {
      const float sv = xb[1024 + t];
      m.S[t >> 4][t & 15] = sv;
      m.ST[t & 15][t >> 4] = sv;
      s_g[((size_t)b << 8) + t] = sv;
    }
    const float2 v2 = *reinterpret_cast<const float2*>(xb + 2048 + (t << 1));
    const int g2 = t << 1;
    const int iv = g2 >> 6, q = g2 & 63;
    m.V[q][iv] = v2.x; m.V[q + 1][iv] = v2.y;
    v_g[ub + (size_t)q * 16 + iv] = v2.x;
    v_g[ub + (size_t)(q + 1) * 16 + iv] = v2.y;
  }
  __syncthreads();
  write_xf_tail(m, t, b, Xf, Xfb, nullptr);
}

// ---------------------------------------------------------------------------
// Pack + classifier fused.
// ---------------------------------------------------------------------------
__global__ __launch_bounds__(256) void pack_cls_kernel(
    const float* __restrict__ outL, float* __restrict__ outT,
    const float* __restrict__ Xf, const float* __restrict__ Wc,
    const float* __restrict__ bc, float* __restrict__ pred,
    float* __restrict__ cls)
{
  const int t = threadIdx.x;
  const int bid = blockIdx.x;
  __shared__ float buf[256 * 9];
  __shared__ float red[4][10];
  {
    const int base = bid << 8;
#pragma unroll
    for (int l = 0; l < 9; ++l)
      buf[t * 9 + l] = outL[(size_t)l * PLANE + base + t];
    __syncthreads();
    const float4* b4 = reinterpret_cast<const float4*>(buf);
    float4* o4 = reinterpret_cast<float4*>(outT + (size_t)base * 9);
    for (int i = t; i < 576; i += 256) o4[i] = b4[i];
  }
  if (bid >= NB) return;
  const int b = bid;
  const int lane = t & 63, w = t >> 6;
  float acc[10];
#pragma unroll
  for (int c = 0; c < 10; ++c) acc[c] = 0.f;
  const float* xr = Xf + ((size_t)b << 12);
  for (int k = t; k < 4096; k += 256) {
    const float x = xr[k];
#pragma unroll
    for (int c = 0; c < 10; ++c) acc[c] += x * Wc[c * 4096 + k];
  }
#pragma unroll
  for (int c = 0; c < 10; ++c)
    for (int off = 32; off; off >>= 1) acc[c] += __shfl_xor(acc[c], off);
  if (lane == 0)
#pragma unroll
    for (int c = 0; c < 10; ++c) red[w][c] = acc[c];
  __syncthreads();
  if (t == 0) {
    float lg[10], ex[10];
    float mx = -1e30f;
#pragma unroll
    for (int c = 0; c < 10; ++c) {
      lg[c] = red[0][c] + red[1][c] + red[2][c] + red[3][c] + bc[c];
      mx = fmaxf(mx, lg[c]);
    }
    float s = 0.f;
#pragma unroll
    for (int c = 0; c < 10; ++c) { ex[c] = expf(lg[c] - mx); s += ex[c]; }
    const float inv = 1.f / s;
#pragma unroll
    for (int c = 0; c < 10; ++c) {
      cls[b * 10 + c] = lg[c];
      pred[b * 10 + c] = ex[c] * inv;
    }
  }
}

extern "C" void kernel_launch(void* const* d_in, const int* in_sizes, int n_in,
                              void* d_out, int out_size, void* d_ws, size_t ws_size,
                              hipStream_t stream) {
  (void)in_sizes; (void)n_in; (void)out_size; (void)ws_size;
  const float* X  = (const float*)d_in[0];
  const float* W0 = (const float*)d_in[1];
  const float* W  = (const float*)d_in[2];
  const float* bb = (const float*)d_in[3];
  const float* Wc = (const float*)d_in[4];
  const float* bc = (const float*)d_in[5];

  float* out_pred  = (float*)d_out;
  float* out_cls   = out_pred + 2560;
  float* out_trans = out_pred + 5120;

  char* ws = (char*)d_ws;
  float* Xf   = (float*)(ws);                      // 4 MB
  u16*   part = (u16*)  (ws + (4ull << 20));       // 16 MB (8 bf16 split-K planes)
  float* u_g  = (float*)(ws + (36ull << 20));      // 1 MB
  float* v_g  = (float*)(ws + (37ull << 20));      // 1 MB
  float* s_g  = (float*)(ws + (38ull << 20));      // 256 KB
  u16*   Xfb  = (u16*)  (ws + (39ull << 20));      // 2 MB
  float* outL = (float*)(ws + (41ull << 20));      // 36 MB (9 layer planes)

  init_kernel<<<NB, 512, 0, stream>>>(X, u_g, v_g, s_g, Xf, Xfb);
  for (int i = 0; i <= 8; ++i) {
    const float* Wl = (i == 0) ? W0 : W + (size_t)(i - 1) * DD * DD;
    gemm_kernel<<<dim3(64, 2 * SPLIT_K), 512, 0, stream>>>(Xfb, Wl, part);
    update_kernel<<<NB, 512, 0, stream>>>(
        part, (i == 0) ? nullptr : (bb + (size_t)(i - 1) * DD),
        u_g, v_g, s_g, Xf, Xfb, outL, i);
  }
  pack_cls_kernel<<<4096, 256, 0, stream>>>(outL, out_trans, Xf, Wc, bc,
                                            out_pred, out_cls);
}

// Round 19
// 399.136 us; speedup vs baseline: 1.0667x; 1.0667x over previous
//
#include <hip/hip_runtime.h>
#include <math.h>

typedef unsigned short u16;
typedef unsigned int u32;
using bf16x8 = __attribute__((ext_vector_type(8))) short;
using f32x4  = __attribute__((ext_vector_type(4))) float;

#define DD 4096
#define NB 256            // batch
#define SPLIT_K 4
#define PSTRIDE (NB * DD) // elements per partial plane
#define PLANE (NB * DD)   // floats per transform layer plane

__device__ __forceinline__ u16 f2bf(float f) {
  unsigned int u = __float_as_uint(f);
  u += 0x7fffu + ((u >> 16) & 1u);   // RNE
  return (u16)(u >> 16);
}
__device__ __forceinline__ float bf2f(u16 h) {
  return __uint_as_float((u32)h << 16);
}
__device__ __forceinline__ unsigned int pack2bf(float a, float b) {
  return (unsigned int)f2bf(a) | ((unsigned int)f2bf(b) << 16);
}
__device__ __forceinline__ void async_cp16(const u16* g, u16* l) {
  __builtin_amdgcn_global_load_lds(
      (const __attribute__((address_space(1))) unsigned int*)g,
      (__attribute__((address_space(3))) unsigned int*)l, 16, 0, 0);
}
__device__ __forceinline__ float dot8bf(const uint4 a, const uint4 b) {
  float s;
  s  = __uint_as_float(a.x << 16) * __uint_as_float(b.x << 16);
  s += __uint_as_float(a.x & 0xffff0000u) * __uint_as_float(b.x & 0xffff0000u);
  s += __uint_as_float(a.y << 16) * __uint_as_float(b.y << 16);
  s += __uint_as_float(a.y & 0xffff0000u) * __uint_as_float(b.y & 0xffff0000u);
  s += __uint_as_float(a.z << 16) * __uint_as_float(b.z << 16);
  s += __uint_as_float(a.z & 0xffff0000u) * __uint_as_float(b.z & 0xffff0000u);
  s += __uint_as_float(a.w << 16) * __uint_as_float(b.w << 16);
  s += __uint_as_float(a.w & 0xffff0000u) * __uint_as_float(b.w & 0xffff0000u);
  return s;
}
__device__ __forceinline__ float dot4f(const float4 a, const float4 b) {
  return a.x * b.x + a.y * b.y + a.z * b.z + a.w * b.w;
}

// ---------------------------------------------------------------------------
// GEMM (R17 config, best measured): tile 128x64, K-chunk 1024 (16 iters),
// grid (64, 8) = 512 WGs = 2 WG/CU, 4 bf16 partial planes.
// ---------------------------------------------------------------------------
__global__ __launch_bounds__(512, 8) void gemm_kernel(
    const u16* __restrict__ A, const float* __restrict__ W,
    u16* __restrict__ part)
{
  const int nt = blockIdx.x;
  const int mt = blockIdx.y & 1;
  const int kz = blockIdx.y >> 1;
  const int t = threadIdx.x;
  const int w = t >> 6, l = t & 63;

  __shared__ __align__(16) u16 As[128 * 64];
  __shared__ __align__(16) u16 Bs[64 * 64];

  const int colg0 = nt << 6;
  const int m0 = mt << 7;
  const int k0 = kz << 10;

  f32x4 acc[2][2];
#pragma unroll
  for (int mi = 0; mi < 2; ++mi)
#pragma unroll
    for (int nj = 0; nj < 2; ++nj)
      acc[mi][nj] = (f32x4){0.f, 0.f, 0.f, 0.f};

  const int wm = w & 3, wn = w >> 2;
  const int lr = l & 15, lg = l >> 4;
  const int arow_l = (w << 3) + (l >> 3);
  const int acl = l & 7;
  const int bn_l = t >> 3;
  const int bcc = t & 7;

  for (int tt = 0; tt < 16; ++tt) {
    const int kk = k0 + (tt << 6);
    __syncthreads();
#pragma unroll
    for (int r2 = 0; r2 < 2; ++r2) {
      const int row = (r2 << 6) + arow_l;
      const int cs = acl ^ (row & 7);
      async_cp16(A + ((size_t)(m0 + row) << 12) + kk + (cs << 3),
                 &As[(r2 << 12) + (w << 9)]);
    }
    {
      const float* wsrc = W + ((size_t)(colg0 + bn_l) << 12) + kk + (bcc << 3);
      const float4 f0 = *reinterpret_cast<const float4*>(wsrc);
      const float4 f1 = *reinterpret_cast<const float4*>(wsrc + 4);
      uint4 pk;
      pk.x = pack2bf(f0.x, f0.y);
      pk.y = pack2bf(f0.z, f0.w);
      pk.z = pack2bf(f1.x, f1.y);
      pk.w = pack2bf(f1.z, f1.w);
      *reinterpret_cast<uint4*>(&Bs[(bn_l << 6) + ((bcc ^ (bn_l & 7)) << 3)]) = pk;
    }
    __syncthreads();
#pragma unroll
    for (int ks = 0; ks < 2; ++ks) {
      const int cg = (ks << 2) + lg;
      bf16x8 av[2], bv[2];
#pragma unroll
      for (int mi = 0; mi < 2; ++mi) {
        const int fr = (wm << 5) + (mi << 4) + lr;
        av[mi] = *reinterpret_cast<const bf16x8*>(&As[(fr << 6) + ((cg ^ (fr & 7)) << 3)]);
      }
#pragma unroll
      for (int nj = 0; nj < 2; ++nj) {
        const int fc = (wn << 5) + (nj << 4) + lr;
        bv[nj] = *reinterpret_cast<const bf16x8*>(&Bs[(fc << 6) + ((cg ^ (fc & 7)) << 3)]);
      }
#pragma unroll
      for (int mi = 0; mi < 2; ++mi)
#pragma unroll
        for (int nj = 0; nj < 2; ++nj)
          acc[mi][nj] = __builtin_amdgcn_mfma_f32_16x16x32_bf16(
              av[mi], bv[nj], acc[mi][nj], 0, 0, 0);
    }
  }

  u16* pout = part + (size_t)kz * PSTRIDE;
#pragma unroll
  for (int mi = 0; mi < 2; ++mi)
#pragma unroll
    for (int nj = 0; nj < 2; ++nj) {
      const int col = colg0 + (wn << 5) + (nj << 4) + lr;
#pragma unroll
      for (int j = 0; j < 4; ++j) {
        const int row = m0 + (wm << 5) + (mi << 4) + (lg << 2) + j;
        pout[((size_t)row << 12) + col] = f2bf(acc[mi][nj][j]);
      }
    }
}

// ---------------------------------------------------------------------------
// Update v4 — 1024 threads: U-side (t<512) and V-side (t>=512) work in
// parallel halves; phase 3 split into 4 concurrent 256-output groups.
// Per-thread serial depth ~halved vs R17.
// ---------------------------------------------------------------------------
struct UpdSmem {
  float U[64][20], V[64][20], P[64][20];
  u16 UTb[16][72], VTb[16][72], PTb[16][72], QTb[16][72];
  float S[16][16], ST[16][16];
  float sinv[16];
  union {
    struct {
      u16 dYb[64][72];
      u16 dYTb[64][80];
    };
    struct {
      float Fu[64][20], Fv[64][20];
      u16 FuTb[16][72], FvTb[16][72];
      float R[16][20], RT[16][20], RvT[16][20];
      float G1u[16][20], G1v[16][20];
      float G2u[16][20], G2v[16][20];
      float M1uT[16][20], M1vT[16][20];
    };
  };
};

// tail (1024 thr): P = U@S (1 out/thread); Xf = P@V^T (4 out/thread)
__device__ __forceinline__ void write_xf_tail(
    UpdSmem& m, int t, int b, float* __restrict__ Xf, u16* __restrict__ Xfb,
    float* __restrict__ outL_plane)
{
  {
    const int p = t >> 4, j = t & 15;
    const float4* u4 = reinterpret_cast<const float4*>(&m.U[p][0]);
    const float4* s4 = reinterpret_cast<const float4*>(&m.ST[j][0]);
    float a = 0.f;
#pragma unroll
    for (int k4 = 0; k4 < 4; ++k4) a += dot4f(u4[k4], s4[k4]);
    m.P[p][j] = a;
  }
  __syncthreads();
  {
    const int p = t >> 4, q0 = (t & 15) << 2;
    float4 pr[4];
    const float4* p4 = reinterpret_cast<const float4*>(&m.P[p][0]);
#pragma unroll
    for (int k4 = 0; k4 < 4; ++k4) pr[k4] = p4[k4];
    float res[4];
#pragma unroll
    for (int e = 0; e < 4; ++e) {
      const float4* v4 = reinterpret_cast<const float4*>(&m.V[q0 + e][0]);
      res[e] = dot4f(pr[0], v4[0]) + dot4f(pr[1], v4[1]) +
               dot4f(pr[2], v4[2]) + dot4f(pr[3], v4[3]);
    }
    const size_t ko = ((size_t)b << 12) + (p << 6) + q0;
    const float4 r0 = make_float4(res[0], res[1], res[2], res[3]);
    *reinterpret_cast<float4*>(Xf + ko) = r0;
    uint2 pk;
    pk.x = pack2bf(res[0], res[1]); pk.y = pack2bf(res[2], res[3]);
    *reinterpret_cast<uint2*>(Xfb + ko) = pk;
    if (outL_plane != nullptr)
      *reinterpret_cast<float4*>(outL_plane + ko) = r0;
  }
}

__global__ __launch_bounds__(1024) void update_kernel(
    const u16* __restrict__ part, const float* __restrict__ bias,
    float* __restrict__ u_g, float* __restrict__ v_g, float* __restrict__ s_g,
    float* __restrict__ Xf, u16* __restrict__ Xfb,
    float* __restrict__ outL, int layer)
{
  const int b = blockIdx.x, t = threadIdx.x;
  __shared__ __align__(16) UpdSmem m;
  float* outL_plane = outL + (size_t)layer * PLANE;
  const size_t ub = (size_t)b << 10;

  // ---- Phase 1: t<512 partials->dY; t>=512 U/V/S loads + bf16 copies ------
  if (t < 512) {
    const u16* p0 = part + ((size_t)b << 12) + (t << 3);
    float x[8];
#pragma unroll
    for (int e = 0; e < 8; ++e) x[e] = 0.f;
#pragma unroll
    for (int kzi = 0; kzi < SPLIT_K; ++kzi) {
      const uint4 v = *reinterpret_cast<const uint4*>(p0 + (size_t)kzi * PSTRIDE);
      x[0] += bf2f((u16)(v.x & 0xffff)); x[1] += bf2f((u16)(v.x >> 16));
      x[2] += bf2f((u16)(v.y & 0xffff)); x[3] += bf2f((u16)(v.y >> 16));
      x[4] += bf2f((u16)(v.z & 0xffff)); x[5] += bf2f((u16)(v.z >> 16));
      x[6] += bf2f((u16)(v.w & 0xffff)); x[7] += bf2f((u16)(v.w >> 16));
    }
    if (bias != nullptr) {
      const float4 b0 = *reinterpret_cast<const float4*>(bias + (t << 3));
      const float4 b1 = *reinterpret_cast<const float4*>(bias + (t << 3) + 4);
      x[0] += b0.x; x[1] += b0.y; x[2] += b0.z; x[3] += b0.w;
      x[4] += b1.x; x[5] += b1.y; x[6] += b1.z; x[7] += b1.w;
    }
#pragma unroll
    for (int e = 0; e < 8; ++e) x[e] = fmaxf(x[e], 0.f);
    const int r2 = t >> 3, c2 = (t & 7) << 3, sw = (t & 7) << 3;
    uint4 pk;
    pk.x = pack2bf(x[0], x[1]); pk.y = pack2bf(x[2], x[3]);
    pk.z = pack2bf(x[4], x[5]); pk.w = pack2bf(x[6], x[7]);
    *reinterpret_cast<uint4*>(&m.dYb[r2][c2]) = pk;
#pragma unroll
    for (int e = 0; e < 8; ++e) m.dYTb[c2 + e][r2 ^ sw] = f2bf(x[e]);
  } else {
    const int tq = t - 512;
    const float2 u2 = *reinterpret_cast<const float2*>(u_g + ub + (tq << 1));
    const float2 v2 = *reinterpret_cast<const float2*>(v_g + ub + (tq << 1));
    const int r = tq >> 3, c = (tq & 7) << 1;
    m.U[r][c] = u2.x; m.U[r][c + 1] = u2.y;
    m.V[r][c] = v2.x; m.V[r][c + 1] = v2.y;
    m.UTb[c][r] = f2bf(u2.x); m.UTb[c + 1][r] = f2bf(u2.y);
    m.VTb[c][r] = f2bf(v2.x); m.VTb[c + 1][r] = f2bf(v2.y);
    if (tq < 256) {
      const float sv = s_g[((size_t)b << 8) + tq];
      m.S[tq >> 4][tq & 15] = sv;
      m.ST[tq & 15][tq >> 4] = sv;
    }
    if (tq < 16) m.sinv[tq] = 1.0f / s_g[((size_t)b << 8) + tq * 17];
  }
  __syncthreads();

  // ---- Phase 2: t<512: 2 P-outputs; t>=512: 2 Q-outputs --------------------
  {
    const int h = t >> 9, tq = t & 511;
    const int p = tq & 63, j0 = (tq >> 6) << 1;
    float a0 = 0.f, a1 = 0.f;
    if (h == 0) {
      const uint4* dy = reinterpret_cast<const uint4*>(&m.dYb[p][0]);
#pragma unroll
      for (int r8 = 0; r8 < 8; ++r8) {
        const uint4 d = dy[r8];
        a0 += dot8bf(d, reinterpret_cast<const uint4*>(&m.VTb[j0][0])[r8]);
        a1 += dot8bf(d, reinterpret_cast<const uint4*>(&m.VTb[j0 + 1][0])[r8]);
      }
      m.PTb[j0][p] = f2bf(a0); m.PTb[j0 + 1][p] = f2bf(a1);
    } else {
      const int sw = (p >> 3) & 7;
      const uint4* dy = reinterpret_cast<const uint4*>(&m.dYTb[p][0]);
#pragma unroll
      for (int r8 = 0; r8 < 8; ++r8) {
        const uint4 d = dy[r8 ^ sw];
        a0 += dot8bf(d, reinterpret_cast<const uint4*>(&m.UTb[j0][0])[r8]);
        a1 += dot8bf(d, reinterpret_cast<const uint4*>(&m.UTb[j0 + 1][0])[r8]);
      }
      m.QTb[j0][p] = f2bf(a0); m.QTb[j0 + 1][p] = f2bf(a1);
    }
  }
  __syncthreads();

  // ---- Phase 3: 4 groups x 256 outputs: R/RT | G2u | RvT | G2v -------------
  {
    const int g = t >> 8, tq = t & 255, i = tq >> 4, j = tq & 15;
    float s = 0.f;
    if (g == 0) {
#pragma unroll
      for (int r8 = 0; r8 < 8; ++r8)
        s += dot8bf(reinterpret_cast<const uint4*>(&m.UTb[i][0])[r8],
                    reinterpret_cast<const uint4*>(&m.PTb[j][0])[r8]);
      m.R[i][j] = s; m.RT[j][i] = s;
    } else if (g == 1) {
#pragma unroll
      for (int r8 = 0; r8 < 8; ++r8)
        s += dot8bf(reinterpret_cast<const uint4*>(&m.UTb[i][0])[r8],
                    reinterpret_cast<const uint4*>(&m.UTb[j][0])[r8]);
      m.G2u[i][j] = s;
    } else if (g == 2) {
#pragma unroll
      for (int r8 = 0; r8 < 8; ++r8)
        s += dot8bf(reinterpret_cast<const uint4*>(&m.VTb[i][0])[r8],
                    reinterpret_cast<const uint4*>(&m.QTb[j][0])[r8]);
      m.RvT[j][i] = s;
    } else {
#pragma unroll
      for (int r8 = 0; r8 < 8; ++r8)
        s += dot8bf(reinterpret_cast<const uint4*>(&m.VTb[i][0])[r8],
                    reinterpret_cast<const uint4*>(&m.VTb[j][0])[r8]);
      m.G2v[i][j] = s;
    }
  }
  __syncthreads();

  // ---- Phase 4: t<512: 2 Fu; t>=512: 2 Fv ----------------------------------
  {
    const int h = t >> 9, tq = t & 511;
    const int p8 = tq >> 3, j0 = (tq << 1) & 15;
    const float s0 = m.sinv[j0], s1 = m.sinv[j0 + 1];
    if (h == 0) {
      float f0 = bf2f(m.PTb[j0][p8]), f1 = bf2f(m.PTb[j0 + 1][p8]);
      const float4* u4 = reinterpret_cast<const float4*>(&m.U[p8][0]);
      const float4* ra = reinterpret_cast<const float4*>(&m.RT[j0][0]);
      const float4* rb = reinterpret_cast<const float4*>(&m.RT[j0 + 1][0]);
#pragma unroll
      for (int k4 = 0; k4 < 4; ++k4) {
        const float4 uu = u4[k4];
        f0 -= dot4f(uu, ra[k4]);
        f1 -= dot4f(uu, rb[k4]);
      }
      f0 *= s0; f1 *= s1;
      *reinterpret_cast<float2*>(&m.Fu[p8][j0]) = make_float2(f0, f1);
      m.FuTb[j0][p8] = f2bf(f0); m.FuTb[j0 + 1][p8] = f2bf(f1);
    } else {
      float g0 = bf2f(m.QTb[j0][p8]), g1 = bf2f(m.QTb[j0 + 1][p8]);
      const float4* v4 = reinterpret_cast<const float4*>(&m.V[p8][0]);
      const float4* rc = reinterpret_cast<const float4*>(&m.RvT[j0][0]);
      const float4* rd = reinterpret_cast<const float4*>(&m.RvT[j0 + 1][0]);
#pragma unroll
      for (int k4 = 0; k4 < 4; ++k4) {
        const float4 vv = v4[k4];
        g0 -= dot4f(vv, rc[k4]);
        g1 -= dot4f(vv, rd[k4]);
      }
      g0 *= s0; g1 *= s1;
      *reinterpret_cast<float2*>(&m.Fv[p8][j0]) = make_float2(g0, g1);
      m.FvTb[j0][p8] = f2bf(g0); m.FvTb[j0 + 1][p8] = f2bf(g1);
    }
  }
  __syncthreads();

  // ---- Phase 5: G1u (t<256) | G1v (t in [256,512)) -------------------------
  if (t < 512) {
    const int g = t >> 8, tq = t & 255, i = tq >> 4, j = tq & 15;
    float s = 0.f;
    if (g == 0) {
#pragma unroll
      for (int r8 = 0; r8 < 8; ++r8)
        s += dot8bf(reinterpret_cast<const uint4*>(&m.UTb[i][0])[r8],
                    reinterpret_cast<const uint4*>(&m.FuTb[j][0])[r8]);
      m.G1u[i][j] = s;
    } else {
#pragma unroll
      for (int r8 = 0; r8 < 8; ++r8)
        s += dot8bf(reinterpret_cast<const uint4*>(&m.VTb[i][0])[r8],
                    reinterpret_cast<const uint4*>(&m.FvTb[j][0])[r8]);
      m.G1v[i][j] = s;
    }
  }
  __syncthreads();

  // ---- Phase 6: M1uT (t<256) | M1vT (t in [256,512)) -----------------------
  if (t < 512) {
    const int g = t >> 8, tq = t & 255, i = tq >> 4, j = tq & 15;
    float mm = 0.f;
    if (g == 0) {
#pragma unroll
      for (int k4 = 0; k4 < 4; ++k4)
        mm += dot4f(reinterpret_cast<const float4*>(&m.G1u[i][0])[k4],
                    reinterpret_cast<const float4*>(&m.G2u[j][0])[k4]);
      m.M1uT[j][i] = mm;
    } else {
#pragma unroll
      for (int k4 = 0; k4 < 4; ++k4)
        mm += dot4f(reinterpret_cast<const float4*>(&m.G1v[i][0])[k4],
                    reinterpret_cast<const float4*>(&m.G2v[j][0])[k4]);
      m.M1vT[j][i] = mm;
    }
  }
  __syncthreads();

  // ---- Phase 7: t<512: U update; t>=512: V update (+S for tq<256) ----------
  {
    const int h = t >> 9, tq = t & 511;
    const int p8 = tq >> 3, j0 = (tq << 1) & 15;
    float n0, n1, ns = 0.f;
    if (h == 0) {
      float du0 = 0.f, du1 = 0.f;
      const float4* fu4 = reinterpret_cast<const float4*>(&m.Fu[p8][0]);
      const float4* ma = reinterpret_cast<const float4*>(&m.M1uT[j0][0]);
      const float4* mb = reinterpret_cast<const float4*>(&m.M1uT[j0 + 1][0]);
#pragma unroll
      for (int k4 = 0; k4 < 4; ++k4) {
        const float4 fu = fu4[k4];
        du0 += dot4f(fu, ma[k4]);
        du1 += dot4f(fu, mb[k4]);
      }
      n0 = m.U[p8][j0]     - 1e-6f * du0;
      n1 = m.U[p8][j0 + 1] - 1e-6f * du1;
    } else {
      float dv0 = 0.f, dv1 = 0.f;
      const float4* fv4 = reinterpret_cast<const float4*>(&m.Fv[p8][0]);
      const float4* mc = reinterpret_cast<const float4*>(&m.M1vT[j0][0]);
      const float4* md = reinterpret_cast<const float4*>(&m.M1vT[j0 + 1][0]);
#pragma unroll
      for (int k4 = 0; k4 < 4; ++k4) {
        const float4 fv = fv4[k4];
        dv0 += dot4f(fv, mc[k4]);
        dv1 += dot4f(fv, md[k4]);
      }
      n0 = m.V[p8][j0]     - 1e-6f * dv0;
      n1 = m.V[p8][j0 + 1] - 1e-6f * dv1;
      if (tq < 256) ns = m.S[tq >> 4][tq & 15] + 1e-3f * m.R[tq >> 4][tq & 15];
    }
    __syncthreads();                 // all reads of old U,V,S,R complete
    if (h == 0) {
      m.U[p8][j0] = n0; m.U[p8][j0 + 1] = n1;
      *reinterpret_cast<float2*>(u_g + ub + (p8 << 4) + j0) = make_float2(n0, n1);
    } else {
      m.V[p8][j0] = n0; m.V[p8][j0 + 1] = n1;
      *reinterpret_cast<float2*>(v_g + ub + (p8 << 4) + j0) = make_float2(n0, n1);
      if (tq < 256) {
        m.S[tq >> 4][tq & 15] = ns;
        m.ST[tq & 15][tq >> 4] = ns;
        s_g[((size_t)b << 8) + tq] = ns;
      }
    }
  }
  __syncthreads();

  write_xf_tail(m, t, b, Xf, Xfb, outL_plane);
}

// ---------------------------------------------------------------------------
// Init (1024 thr): unpack u, s, v; Xf0 = u s v^T.
// ---------------------------------------------------------------------------
__global__ __launch_bounds__(1024) void init_kernel(
    const float* __restrict__ X, float* __restrict__ u_g, float* __restrict__ v_g,
    float* __restrict__ s_g, float* __restrict__ Xf, u16* __restrict__ Xfb)
{
  const int b = blockIdx.x, t = threadIdx.x;
  __shared__ __align__(16) UpdSmem m;
  const float* xb = X + (size_t)b * 3072;
  const size_t ub = (size_t)b << 10;
  if (t < 512) {
    const float2 u2 = *reinterpret_cast<const float2*>(xb + (t << 1));
    const int r = t >> 3, c = (t & 7) << 1;
    m.U[r][c] = u2.x; m.U[r][c + 1] = u2.y;
    *reinterpret_cast<float2*>(u_g + ub + (t << 1)) = u2;
  } else {
    const int tq = t - 512;
    const float2 v2 = *reinterpret_cast<const float2*>(xb + 2048 + (tq << 1));
    const int g2 = tq << 1;
    const int iv = g2 >> 6, q = g2 & 63;
    m.V[q][iv] = v2.x; m.V[q + 1][iv] = v2.y;
    v_g[ub + (size_t)q * 16 + iv] = v2.x;
    v_g[ub + (size_t)(q + 1) * 16 + iv] = v2.y;
    if (tq < 256) {
      const float sv = xb[1024 + tq];
      m.S[tq >> 4][tq & 15] = sv;
      m.ST[tq & 15][tq >> 4] = sv;
      s_g[((size_t)b << 8) + tq] = sv;
    }
  }
  __syncthreads();
  write_xf_tail(m, t, b, Xf, Xfb, nullptr);
}

// ---------------------------------------------------------------------------
// Pack + classifier fused.
// ---------------------------------------------------------------------------
__global__ __launch_bounds__(256) void pack_cls_kernel(
    const float* __restrict__ outL, float* __restrict__ outT,
    const float* __restrict__ Xf, const float* __restrict__ Wc,
    const float* __restrict__ bc, float* __restrict__ pred,
    float* __restrict__ cls)
{
  const int t = threadIdx.x;
  const int bid = blockIdx.x;
  __shared__ float buf[256 * 9];
  __shared__ float red[4][10];
  {
    const int base = bid << 8;
#pragma unroll
    for (int l = 0; l < 9; ++l)
      buf[t * 9 + l] = outL[(size_t)l * PLANE + base + t];
    __syncthreads();
    const float4* b4 = reinterpret_cast<const float4*>(buf);
    float4* o4 = reinterpret_cast<float4*>(outT + (size_t)base * 9);
    for (int i = t; i < 576; i += 256) o4[i] = b4[i];
  }
  if (bid >= NB) return;
  const int b = bid;
  const int lane = t & 63, w = t >> 6;
  float acc[10];
#pragma unroll
  for (int c = 0; c < 10; ++c) acc[c] = 0.f;
  const float* xr = Xf + ((size_t)b << 12);
  for (int k = t; k < 4096; k += 256) {
    const float x = xr[k];
#pragma unroll
    for (int c = 0; c < 10; ++c) acc[c] += x * Wc[c * 4096 + k];
  }
#pragma unroll
  for (int c = 0; c < 10; ++c)
    for (int off = 32; off; off >>= 1) acc[c] += __shfl_xor(acc[c], off);
  if (lane == 0)
#pragma unroll
    for (int c = 0; c < 10; ++c) red[w][c] = acc[c];
  __syncthreads();
  if (t == 0) {
    float lg[10], ex[10];
    float mx = -1e30f;
#pragma unroll
    for (int c = 0; c < 10; ++c) {
      lg[c] = red[0][c] + red[1][c] + red[2][c] + red[3][c] + bc[c];
      mx = fmaxf(mx, lg[c]);
    }
    float s = 0.f;
#pragma unroll
    for (int c = 0; c < 10; ++c) { ex[c] = expf(lg[c] - mx); s += ex[c]; }
    const float inv = 1.f / s;
#pragma unroll
    for (int c = 0; c < 10; ++c) {
      cls[b * 10 + c] = lg[c];
      pred[b * 10 + c] = ex[c] * inv;
    }
  }
}

extern "C" void kernel_launch(void* const* d_in, const int* in_sizes, int n_in,
                              void* d_out, int out_size, void* d_ws, size_t ws_size,
                              hipStream_t stream) {
  (void)in_sizes; (void)n_in; (void)out_size; (void)ws_size;
  const float* X  = (const float*)d_in[0];
  const float* W0 = (const float*)d_in[1];
  const float* W  = (const float*)d_in[2];
  const float* bb = (const float*)d_in[3];
  const float* Wc = (const float*)d_in[4];
  const float* bc = (const float*)d_in[5];

  float* out_pred  = (float*)d_out;
  float* out_cls   = out_pred + 2560;
  float* out_trans = out_pred + 5120;

  char* ws = (char*)d_ws;
  float* Xf   = (float*)(ws);                      // 4 MB
  u16*   part = (u16*)  (ws + (4ull << 20));       // 8 MB (4 bf16 split-K planes)
  float* u_g  = (float*)(ws + (36ull << 20));      // 1 MB
  float* v_g  = (float*)(ws + (37ull << 20));      // 1 MB
  float* s_g  = (float*)(ws + (38ull << 20));      // 256 KB
  u16*   Xfb  = (u16*)  (ws + (39ull << 20));      // 2 MB
  float* outL = (float*)(ws + (41ull << 20));      // 36 MB (9 layer planes)

  init_kernel<<<NB, 1024, 0, stream>>>(X, u_g, v_g, s_g, Xf, Xfb);
  for (int i = 0; i <= 8; ++i) {
    const float* Wl = (i == 0) ? W0 : W + (size_t)(i - 1) * DD * DD;
    gemm_kernel<<<dim3(64, 2 * SPLIT_K), 512, 0, stream>>>(Xfb, Wl, part);
    update_kernel<<<NB, 1024, 0, stream>>>(
        part, (i == 0) ? nullptr : (bb + (size_t)(i - 1) * DD),
        u_g, v_g, s_g, Xf, Xfb, outL, i);
  }
  pack_cls_kernel<<<4096, 256, 0, stream>>>(outL, out_trans, Xf, Wc, bc,
                                            out_pred, out_cls);
}

// Round 20
// 393.874 us; speedup vs baseline: 1.0809x; 1.0134x over previous
//
#include <hip/hip_runtime.h>
#include <math.h>

typedef unsigned short u16;
typedef unsigned int u32;
using bf16x8 = __attribute__((ext_vector_type(8))) short;
using f32x4  = __attribute__((ext_vector_type(4))) float;

#define DD 4096
#define NB 256            // batch
#define SPLIT_K 4
#define PSTRIDE (NB * DD) // elements per partial plane
#define PLANE (NB * DD)   // floats per transform layer plane

__device__ __forceinline__ u16 f2bf(float f) {
  unsigned int u = __float_as_uint(f);
  u += 0x7fffu + ((u >> 16) & 1u);   // RNE
  return (u16)(u >> 16);
}
__device__ __forceinline__ float bf2f(u16 h) {
  return __uint_as_float((u32)h << 16);
}
__device__ __forceinline__ unsigned int pack2bf(float a, float b) {
  return (unsigned int)f2bf(a) | ((unsigned int)f2bf(b) << 16);
}
__device__ __forceinline__ void async_cp16(const u16* g, u16* l) {
  __builtin_amdgcn_global_load_lds(
      (const __attribute__((address_space(1))) unsigned int*)g,
      (__attribute__((address_space(3))) unsigned int*)l, 16, 0, 0);
}
__device__ __forceinline__ float dot8bf(const uint4 a, const uint4 b) {
  float s;
  s  = __uint_as_float(a.x << 16) * __uint_as_float(b.x << 16);
  s += __uint_as_float(a.x & 0xffff0000u) * __uint_as_float(b.x & 0xffff0000u);
  s += __uint_as_float(a.y << 16) * __uint_as_float(b.y << 16);
  s += __uint_as_float(a.y & 0xffff0000u) * __uint_as_float(b.y & 0xffff0000u);
  s += __uint_as_float(a.z << 16) * __uint_as_float(b.z << 16);
  s += __uint_as_float(a.z & 0xffff0000u) * __uint_as_float(b.z & 0xffff0000u);
  s += __uint_as_float(a.w << 16) * __uint_as_float(b.w << 16);
  s += __uint_as_float(a.w & 0xffff0000u) * __uint_as_float(b.w & 0xffff0000u);
  return s;
}
__device__ __forceinline__ float dot4f(const float4 a, const float4 b) {
  return a.x * b.x + a.y * b.y + a.z * b.z + a.w * b.w;
}

// ---------------------------------------------------------------------------
// GEMM (best measured config): tile 128x64, K-chunk 1024 (16 iters),
// grid (64, 8) = 512 WGs = 2 WG/CU, 4 bf16 partial planes.
// ---------------------------------------------------------------------------
__global__ __launch_bounds__(512, 8) void gemm_kernel(
    const u16* __restrict__ A, const float* __restrict__ W,
    u16* __restrict__ part)
{
  const int nt = blockIdx.x;
  const int mt = blockIdx.y & 1;
  const int kz = blockIdx.y >> 1;
  const int t = threadIdx.x;
  const int w = t >> 6, l = t & 63;

  __shared__ __align__(16) u16 As[128 * 64];
  __shared__ __align__(16) u16 Bs[64 * 64];

  const int colg0 = nt << 6;
  const int m0 = mt << 7;
  const int k0 = kz << 10;

  f32x4 acc[2][2];
#pragma unroll
  for (int mi = 0; mi < 2; ++mi)
#pragma unroll
    for (int nj = 0; nj < 2; ++nj)
      acc[mi][nj] = (f32x4){0.f, 0.f, 0.f, 0.f};

  const int wm = w & 3, wn = w >> 2;
  const int lr = l & 15, lg = l >> 4;
  const int arow_l = (w << 3) + (l >> 3);
  const int acl = l & 7;
  const int bn_l = t >> 3;
  const int bcc = t & 7;

  for (int tt = 0; tt < 16; ++tt) {
    const int kk = k0 + (tt << 6);
    __syncthreads();
#pragma unroll
    for (int r2 = 0; r2 < 2; ++r2) {
      const int row = (r2 << 6) + arow_l;
      const int cs = acl ^ (row & 7);
      async_cp16(A + ((size_t)(m0 + row) << 12) + kk + (cs << 3),
                 &As[(r2 << 12) + (w << 9)]);
    }
    {
      const float* wsrc = W + ((size_t)(colg0 + bn_l) << 12) + kk + (bcc << 3);
      const float4 f0 = *reinterpret_cast<const float4*>(wsrc);
      const float4 f1 = *reinterpret_cast<const float4*>(wsrc + 4);
      uint4 pk;
      pk.x = pack2bf(f0.x, f0.y);
      pk.y = pack2bf(f0.z, f0.w);
      pk.z = pack2bf(f1.x, f1.y);
      pk.w = pack2bf(f1.z, f1.w);
      *reinterpret_cast<uint4*>(&Bs[(bn_l << 6) + ((bcc ^ (bn_l & 7)) << 3)]) = pk;
    }
    __syncthreads();
#pragma unroll
    for (int ks = 0; ks < 2; ++ks) {
      const int cg = (ks << 2) + lg;
      bf16x8 av[2], bv[2];
#pragma unroll
      for (int mi = 0; mi < 2; ++mi) {
        const int fr = (wm << 5) + (mi << 4) + lr;
        av[mi] = *reinterpret_cast<const bf16x8*>(&As[(fr << 6) + ((cg ^ (fr & 7)) << 3)]);
      }
#pragma unroll
      for (int nj = 0; nj < 2; ++nj) {
        const int fc = (wn << 5) + (nj << 4) + lr;
        bv[nj] = *reinterpret_cast<const bf16x8*>(&Bs[(fc << 6) + ((cg ^ (fc & 7)) << 3)]);
      }
#pragma unroll
      for (int mi = 0; mi < 2; ++mi)
#pragma unroll
        for (int nj = 0; nj < 2; ++nj)
          acc[mi][nj] = __builtin_amdgcn_mfma_f32_16x16x32_bf16(
              av[mi], bv[nj], acc[mi][nj], 0, 0, 0);
    }
  }

  u16* pout = part + (size_t)kz * PSTRIDE;
#pragma unroll
  for (int mi = 0; mi < 2; ++mi)
#pragma unroll
    for (int nj = 0; nj < 2; ++nj) {
      const int col = colg0 + (wn << 5) + (nj << 4) + lr;
#pragma unroll
      for (int j = 0; j < 4; ++j) {
        const int row = m0 + (wm << 5) + (mi << 4) + (lg << 2) + j;
        pout[((size_t)row << 12) + col] = f2bf(acc[mi][nj][j]);
      }
    }
}

// ---------------------------------------------------------------------------
// Update v4 (R19 body, 1024 thr) with f32 Xf buffer removed: outL plane
// carries the f32 result (classifier reads plane 8).
// ---------------------------------------------------------------------------
struct UpdSmem {
  float U[64][20], V[64][20], P[64][20];
  u16 UTb[16][72], VTb[16][72], PTb[16][72], QTb[16][72];
  float S[16][16], ST[16][16];
  float sinv[16];
  union {
    struct {
      u16 dYb[64][72];
      u16 dYTb[64][80];
    };
    struct {
      float Fu[64][20], Fv[64][20];
      u16 FuTb[16][72], FvTb[16][72];
      float R[16][20], RT[16][20], RvT[16][20];
      float G1u[16][20], G1v[16][20];
      float G2u[16][20], G2v[16][20];
      float M1uT[16][20], M1vT[16][20];
    };
  };
};

// tail (1024 thr): P = U@S (1 out/thread); Xf = P@V^T (4 out/thread)
__device__ __forceinline__ void write_xf_tail(
    UpdSmem& m, int t, int b, u16* __restrict__ Xfb,
    float* __restrict__ outL_plane)
{
  {
    const int p = t >> 4, j = t & 15;
    const float4* u4 = reinterpret_cast<const float4*>(&m.U[p][0]);
    const float4* s4 = reinterpret_cast<const float4*>(&m.ST[j][0]);
    float a = 0.f;
#pragma unroll
    for (int k4 = 0; k4 < 4; ++k4) a += dot4f(u4[k4], s4[k4]);
    m.P[p][j] = a;
  }
  __syncthreads();
  {
    const int p = t >> 4, q0 = (t & 15) << 2;
    float4 pr[4];
    const float4* p4 = reinterpret_cast<const float4*>(&m.P[p][0]);
#pragma unroll
    for (int k4 = 0; k4 < 4; ++k4) pr[k4] = p4[k4];
    float res[4];
#pragma unroll
    for (int e = 0; e < 4; ++e) {
      const float4* v4 = reinterpret_cast<const float4*>(&m.V[q0 + e][0]);
      res[e] = dot4f(pr[0], v4[0]) + dot4f(pr[1], v4[1]) +
               dot4f(pr[2], v4[2]) + dot4f(pr[3], v4[3]);
    }
    const size_t ko = ((size_t)b << 12) + (p << 6) + q0;
    uint2 pk;
    pk.x = pack2bf(res[0], res[1]); pk.y = pack2bf(res[2], res[3]);
    *reinterpret_cast<uint2*>(Xfb + ko) = pk;
    if (outL_plane != nullptr)
      *reinterpret_cast<float4*>(outL_plane + ko) =
          make_float4(res[0], res[1], res[2], res[3]);
  }
}

__global__ __launch_bounds__(1024) void update_kernel(
    const u16* __restrict__ part, const float* __restrict__ bias,
    float* __restrict__ u_g, float* __restrict__ v_g, float* __restrict__ s_g,
    u16* __restrict__ Xfb, float* __restrict__ outL, int layer)
{
  const int b = blockIdx.x, t = threadIdx.x;
  __shared__ __align__(16) UpdSmem m;
  float* outL_plane = outL + (size_t)layer * PLANE;
  const size_t ub = (size_t)b << 10;

  // ---- Phase 1: t<512 partials->dY; t>=512 U/V/S loads + bf16 copies ------
  if (t < 512) {
    const u16* p0 = part + ((size_t)b << 12) + (t << 3);
    float x[8];
#pragma unroll
    for (int e = 0; e < 8; ++e) x[e] = 0.f;
#pragma unroll
    for (int kzi = 0; kzi < SPLIT_K; ++kzi) {
      const uint4 v = *reinterpret_cast<const uint4*>(p0 + (size_t)kzi * PSTRIDE);
      x[0] += bf2f((u16)(v.x & 0xffff)); x[1] += bf2f((u16)(v.x >> 16));
      x[2] += bf2f((u16)(v.y & 0xffff)); x[3] += bf2f((u16)(v.y >> 16));
      x[4] += bf2f((u16)(v.z & 0xffff)); x[5] += bf2f((u16)(v.z >> 16));
      x[6] += bf2f((u16)(v.w & 0xffff)); x[7] += bf2f((u16)(v.w >> 16));
    }
    if (bias != nullptr) {
      const float4 b0 = *reinterpret_cast<const float4*>(bias + (t << 3));
      const float4 b1 = *reinterpret_cast<const float4*>(bias + (t << 3) + 4);
      x[0] += b0.x; x[1] += b0.y; x[2] += b0.z; x[3] += b0.w;
      x[4] += b1.x; x[5] += b1.y; x[6] += b1.z; x[7] += b1.w;
    }
#pragma unroll
    for (int e = 0; e < 8; ++e) x[e] = fmaxf(x[e], 0.f);
    const int r2 = t >> 3, c2 = (t & 7) << 3, sw = (t & 7) << 3;
    uint4 pk;
    pk.x = pack2bf(x[0], x[1]); pk.y = pack2bf(x[2], x[3]);
    pk.z = pack2bf(x[4], x[5]); pk.w = pack2bf(x[6], x[7]);
    *reinterpret_cast<uint4*>(&m.dYb[r2][c2]) = pk;
#pragma unroll
    for (int e = 0; e < 8; ++e) m.dYTb[c2 + e][r2 ^ sw] = f2bf(x[e]);
  } else {
    const int tq = t - 512;
    const float2 u2 = *reinterpret_cast<const float2*>(u_g + ub + (tq << 1));
    const float2 v2 = *reinterpret_cast<const float2*>(v_g + ub + (tq << 1));
    const int r = tq >> 3, c = (tq & 7) << 1;
    m.U[r][c] = u2.x; m.U[r][c + 1] = u2.y;
    m.V[r][c] = v2.x; m.V[r][c + 1] = v2.y;
    m.UTb[c][r] = f2bf(u2.x); m.UTb[c + 1][r] = f2bf(u2.y);
    m.VTb[c][r] = f2bf(v2.x); m.VTb[c + 1][r] = f2bf(v2.y);
    if (tq < 256) {
      const float sv = s_g[((size_t)b << 8) + tq];
      m.S[tq >> 4][tq & 15] = sv;
      m.ST[tq & 15][tq >> 4] = sv;
    }
    if (tq < 16) m.sinv[tq] = 1.0f / s_g[((size_t)b << 8) + tq * 17];
  }
  __syncthreads();

  // ---- Phase 2: t<512: 2 P-outputs; t>=512: 2 Q-outputs --------------------
  {
    const int h = t >> 9, tq = t & 511;
    const int p = tq & 63, j0 = (tq >> 6) << 1;
    float a0 = 0.f, a1 = 0.f;
    if (h == 0) {
      const uint4* dy = reinterpret_cast<const uint4*>(&m.dYb[p][0]);
#pragma unroll
      for (int r8 = 0; r8 < 8; ++r8) {
        const uint4 d = dy[r8];
        a0 += dot8bf(d, reinterpret_cast<const uint4*>(&m.VTb[j0][0])[r8]);
        a1 += dot8bf(d, reinterpret_cast<const uint4*>(&m.VTb[j0 + 1][0])[r8]);
      }
      m.PTb[j0][p] = f2bf(a0); m.PTb[j0 + 1][p] = f2bf(a1);
    } else {
      const int sw = (p >> 3) & 7;
      const uint4* dy = reinterpret_cast<const uint4*>(&m.dYTb[p][0]);
#pragma unroll
      for (int r8 = 0; r8 < 8; ++r8) {
        const uint4 d = dy[r8 ^ sw];
        a0 += dot8bf(d, reinterpret_cast<const uint4*>(&m.UTb[j0][0])[r8]);
        a1 += dot8bf(d, reinterpret_cast<const uint4*>(&m.UTb[j0 + 1][0])[r8]);
      }
      m.QTb[j0][p] = f2bf(a0); m.QTb[j0 + 1][p] = f2bf(a1);
    }
  }
  __syncthreads();

  // ---- Phase 3: 4 groups x 256 outputs: R/RT | G2u | RvT | G2v -------------
  {
    const int g = t >> 8, tq = t & 255, i = tq >> 4, j = tq & 15;
    float s = 0.f;
    if (g == 0) {
#pragma unroll
      for (int r8 = 0; r8 < 8; ++r8)
        s += dot8bf(reinterpret_cast<const uint4*>(&m.UTb[i][0])[r8],
                    reinterpret_cast<const uint4*>(&m.PTb[j][0])[r8]);
      m.R[i][j] = s; m.RT[j][i] = s;
    } else if (g == 1) {
#pragma unroll
      for (int r8 = 0; r8 < 8; ++r8)
        s += dot8bf(reinterpret_cast<const uint4*>(&m.UTb[i][0])[r8],
                    reinterpret_cast<const uint4*>(&m.UTb[j][0])[r8]);
      m.G2u[i][j] = s;
    } else if (g == 2) {
#pragma unroll
      for (int r8 = 0; r8 < 8; ++r8)
        s += dot8bf(reinterpret_cast<const uint4*>(&m.VTb[i][0])[r8],
                    reinterpret_cast<const uint4*>(&m.QTb[j][0])[r8]);
      m.RvT[j][i] = s;
    } else {
#pragma unroll
      for (int r8 = 0; r8 < 8; ++r8)
        s += dot8bf(reinterpret_cast<const uint4*>(&m.VTb[i][0])[r8],
                    reinterpret_cast<const uint4*>(&m.VTb[j][0])[r8]);
      m.G2v[i][j] = s;
    }
  }
  __syncthreads();

  // ---- Phase 4: t<512: 2 Fu; t>=512: 2 Fv ----------------------------------
  {
    const int h = t >> 9, tq = t & 511;
    const int p8 = tq >> 3, j0 = (tq << 1) & 15;
    const float s0 = m.sinv[j0], s1 = m.sinv[j0 + 1];
    if (h == 0) {
      float f0 = bf2f(m.PTb[j0][p8]), f1 = bf2f(m.PTb[j0 + 1][p8]);
      const float4* u4 = reinterpret_cast<const float4*>(&m.U[p8][0]);
      const float4* ra = reinterpret_cast<const float4*>(&m.RT[j0][0]);
      const float4* rb = reinterpret_cast<const float4*>(&m.RT[j0 + 1][0]);
#pragma unroll
      for (int k4 = 0; k4 < 4; ++k4) {
        const float4 uu = u4[k4];
        f0 -= dot4f(uu, ra[k4]);
        f1 -= dot4f(uu, rb[k4]);
      }
      f0 *= s0; f1 *= s1;
      *reinterpret_cast<float2*>(&m.Fu[p8][j0]) = make_float2(f0, f1);
      m.FuTb[j0][p8] = f2bf(f0); m.FuTb[j0 + 1][p8] = f2bf(f1);
    } else {
      float g0 = bf2f(m.QTb[j0][p8]), g1 = bf2f(m.QTb[j0 + 1][p8]);
      const float4* v4 = reinterpret_cast<const float4*>(&m.V[p8][0]);
      const float4* rc = reinterpret_cast<const float4*>(&m.RvT[j0][0]);
      const float4* rd = reinterpret_cast<const float4*>(&m.RvT[j0 + 1][0]);
#pragma unroll
      for (int k4 = 0; k4 < 4; ++k4) {
        const float4 vv = v4[k4];
        g0 -= dot4f(vv, rc[k4]);
        g1 -= dot4f(vv, rd[k4]);
      }
      g0 *= s0; g1 *= s1;
      *reinterpret_cast<float2*>(&m.Fv[p8][j0]) = make_float2(g0, g1);
      m.FvTb[j0][p8] = f2bf(g0); m.FvTb[j0 + 1][p8] = f2bf(g1);
    }
  }
  __syncthreads();

  // ---- Phase 5: G1u (t<256) | G1v (t in [256,512)) -------------------------
  if (t < 512) {
    const int g = t >> 8, tq = t & 255, i = tq >> 4, j = tq & 15;
    float s = 0.f;
    if (g == 0) {
#pragma unroll
      for (int r8 = 0; r8 < 8; ++r8)
        s += dot8bf(reinterpret_cast<const uint4*>(&m.UTb[i][0])[r8],
                    reinterpret_cast<const uint4*>(&m.FuTb[j][0])[r8]);
      m.G1u[i][j] = s;
    } else {
#pragma unroll
      for (int r8 = 0; r8 < 8; ++r8)
        s += dot8bf(reinterpret_cast<const uint4*>(&m.VTb[i][0])[r8],
                    reinterpret_cast<const uint4*>(&m.FvTb[j][0])[r8]);
      m.G1v[i][j] = s;
    }
  }
  __syncthreads();

  // ---- Phase 6: M1uT (t<256) | M1vT (t in [256,512)) -----------------------
  if (t < 512) {
    const int g = t >> 8, tq = t & 255, i = tq >> 4, j = tq & 15;
    float mm = 0.f;
    if (g == 0) {
#pragma unroll
      for (int k4 = 0; k4 < 4; ++k4)
        mm += dot4f(reinterpret_cast<const float4*>(&m.G1u[i][0])[k4],
                    reinterpret_cast<const float4*>(&m.G2u[j][0])[k4]);
      m.M1uT[j][i] = mm;
    } else {
#pragma unroll
      for (int k4 = 0; k4 < 4; ++k4)
        mm += dot4f(reinterpret_cast<const float4*>(&m.G1v[i][0])[k4],
                    reinterpret_cast<const float4*>(&m.G2v[j][0])[k4]);
      m.M1vT[j][i] = mm;
    }
  }
  __syncthreads();

  // ---- Phase 7: t<512: U update; t>=512: V update (+S for tq<256) ----------
  {
    const int h = t >> 9, tq = t & 511;
    const int p8 = tq >> 3, j0 = (tq << 1) & 15;
    float n0, n1, ns = 0.f;
    if (h == 0) {
      float du0 = 0.f, du1 = 0.f;
      const float4* fu4 = reinterpret_cast<const float4*>(&m.Fu[p8][0]);
      const float4* ma = reinterpret_cast<const float4*>(&m.M1uT[j0][0]);
      const float4* mb = reinterpret_cast<const float4*>(&m.M1uT[j0 + 1][0]);
#pragma unroll
      for (int k4 = 0; k4 < 4; ++k4) {
        const float4 fu = fu4[k4];
        du0 += dot4f(fu, ma[k4]);
        du1 += dot4f(fu, mb[k4]);
      }
      n0 = m.U[p8][j0]     - 1e-6f * du0;
      n1 = m.U[p8][j0 + 1] - 1e-6f * du1;
    } else {
      float dv0 = 0.f, dv1 = 0.f;
      const float4* fv4 = reinterpret_cast<const float4*>(&m.Fv[p8][0]);
      const float4* mc = reinterpret_cast<const float4*>(&m.M1vT[j0][0]);
      const float4* md = reinterpret_cast<const float4*>(&m.M1vT[j0 + 1][0]);
#pragma unroll
      for (int k4 = 0; k4 < 4; ++k4) {
        const float4 fv = fv4[k4];
        dv0 += dot4f(fv, mc[k4]);
        dv1 += dot4f(fv, md[k4]);
      }
      n0 = m.V[p8][j0]     - 1e-6f * dv0;
      n1 = m.V[p8][j0 + 1] - 1e-6f * dv1;
      if (tq < 256) ns = m.S[tq >> 4][tq & 15] + 1e-3f * m.R[tq >> 4][tq & 15];
    }
    __syncthreads();                 // all reads of old U,V,S,R complete
    if (h == 0) {
      m.U[p8][j0] = n0; m.U[p8][j0 + 1] = n1;
      *reinterpret_cast<float2*>(u_g + ub + (p8 << 4) + j0) = make_float2(n0, n1);
    } else {
      m.V[p8][j0] = n0; m.V[p8][j0 + 1] = n1;
      *reinterpret_cast<float2*>(v_g + ub + (p8 << 4) + j0) = make_float2(n0, n1);
      if (tq < 256) {
        m.S[tq >> 4][tq & 15] = ns;
        m.ST[tq & 15][tq >> 4] = ns;
        s_g[((size_t)b << 8) + tq] = ns;
      }
    }
  }
  __syncthreads();

  write_xf_tail(m, t, b, Xfb, outL_plane);
}

// ---------------------------------------------------------------------------
// Init (1024 thr): unpack u, s, v; Xfb0 = bf16(u s v^T).
// ---------------------------------------------------------------------------
__global__ __launch_bounds__(1024) void init_kernel(
    const float* __restrict__ X, float* __restrict__ u_g, float* __restrict__ v_g,
    float* __restrict__ s_g, u16* __restrict__ Xfb)
{
  const int b = blockIdx.x, t = threadIdx.x;
  __shared__ __align__(16) UpdSmem m;
  const float* xb = X + (size_t)b * 3072;
  const size_t ub = (size_t)b << 10;
  if (t < 512) {
    const float2 u2 = *reinterpret_cast<const float2*>(xb + (t << 1));
    const int r = t >> 3, c = (t & 7) << 1;
    m.U[r][c] = u2.x; m.U[r][c + 1] = u2.y;
    *reinterpret_cast<float2*>(u_g + ub + (t << 1)) = u2;
  } else {
    const int tq = t - 512;
    const float2 v2 = *reinterpret_cast<const float2*>(xb + 2048 + (tq << 1));
    const int g2 = tq << 1;
    const int iv = g2 >> 6, q = g2 & 63;
    m.V[q][iv] = v2.x; m.V[q + 1][iv] = v2.y;
    v_g[ub + (size_t)q * 16 + iv] = v2.x;
    v_g[ub + (size_t)(q + 1) * 16 + iv] = v2.y;
    if (tq < 256) {
      const float sv = xb[1024 + tq];
      m.S[tq >> 4][tq & 15] = sv;
      m.ST[tq & 15][tq >> 4] = sv;
      s_g[((size_t)b << 8) + tq] = sv;
    }
  }
  __syncthreads();
  write_xf_tail(m, t, b, Xfb, nullptr);
}

// ---------------------------------------------------------------------------
// Pack + classifier fused; classifier reads outL plane 8 (final Xf, f32).
// ---------------------------------------------------------------------------
__global__ __launch_bounds__(256) void pack_cls_kernel(
    const float* __restrict__ outL, float* __restrict__ outT,
    const float* __restrict__ Wc, const float* __restrict__ bc,
    float* __restrict__ pred, float* __restrict__ cls)
{
  const int t = threadIdx.x;
  const int bid = blockIdx.x;
  __shared__ float buf[256 * 9];
  __shared__ float red[4][10];
  {
    const int base = bid << 8;
#pragma unroll
    for (int l = 0; l < 9; ++l)
      buf[t * 9 + l] = outL[(size_t)l * PLANE + base + t];
    __syncthreads();
    const float4* b4 = reinterpret_cast<const float4*>(buf);
    float4* o4 = reinterpret_cast<float4*>(outT + (size_t)base * 9);
    for (int i = t; i < 576; i += 256) o4[i] = b4[i];
  }
  if (bid >= NB) return;
  const int b = bid;
  const int lane = t & 63, w = t >> 6;
  float acc[10];
#pragma unroll
  for (int c = 0; c < 10; ++c) acc[c] = 0.f;
  const float* xr = outL + (size_t)8 * PLANE + ((size_t)b << 12);
  for (int k = t; k < 4096; k += 256) {
    const float x = xr[k];
#pragma unroll
    for (int c = 0; c < 10; ++c) acc[c] += x * Wc[c * 4096 + k];
  }
#pragma unroll
  for (int c = 0; c < 10; ++c)
    for (int off = 32; off; off >>= 1) acc[c] += __shfl_xor(acc[c], off);
  if (lane == 0)
#pragma unroll
    for (int c = 0; c < 10; ++c) red[w][c] = acc[c];
  __syncthreads();
  if (t == 0) {
    float lg[10], ex[10];
    float mx = -1e30f;
#pragma unroll
    for (int c = 0; c < 10; ++c) {
      lg[c] = red[0][c] + red[1][c] + red[2][c] + red[3][c] + bc[c];
      mx = fmaxf(mx, lg[c]);
    }
    float s = 0.f;
#pragma unroll
    for (int c = 0; c < 10; ++c) { ex[c] = expf(lg[c] - mx); s += ex[c]; }
    const float inv = 1.f / s;
#pragma unroll
    for (int c = 0; c < 10; ++c) {
      cls[b * 10 + c] = lg[c];
      pred[b * 10 + c] = ex[c] * inv;
    }
  }
}

extern "C" void kernel_launch(void* const* d_in, const int* in_sizes, int n_in,
                              void* d_out, int out_size, void* d_ws, size_t ws_size,
                              hipStream_t stream) {
  (void)in_sizes; (void)n_in; (void)out_size; (void)ws_size;
  const float* X  = (const float*)d_in[0];
  const float* W0 = (const float*)d_in[1];
  const float* W  = (const float*)d_in[2];
  const float* bb = (const float*)d_in[3];
  const float* Wc = (const float*)d_in[4];
  const float* bc = (const float*)d_in[5];

  float* out_pred  = (float*)d_out;
  float* out_cls   = out_pred + 2560;
  float* out_trans = out_pred + 5120;

  char* ws = (char*)d_ws;
  u16*   part = (u16*)  (ws + (4ull << 20));       // 8 MB (4 bf16 split-K planes)
  float* u_g  = (float*)(ws + (36ull << 20));      // 1 MB
  float* v_g  = (float*)(ws + (37ull << 20));      // 1 MB
  float* s_g  = (float*)(ws + (38ull << 20));      // 256 KB
  u16*   Xfb  = (u16*)  (ws + (39ull << 20));      // 2 MB
  float* outL = (float*)(ws + (41ull << 20));      // 36 MB (9 layer planes)

  init_kernel<<<NB, 1024, 0, stream>>>(X, u_g, v_g, s_g, Xfb);
  for (int i = 0; i <= 8; ++i) {
    const float* Wl = (i == 0) ? W0 : W + (size_t)(i - 1) * DD * DD;
    gemm_kernel<<<dim3(64, 2 * SPLIT_K), 512, 0, stream>>>(Xfb, Wl, part);
    update_kernel<<<NB, 1024, 0, stream>>>(
        part, (i == 0) ? nullptr : (bb + (size_t)(i - 1) * DD),
        u_g, v_g, s_g, Xfb, outL, i);
  }
  pack_cls_kernel<<<4096, 256, 0, stream>>>(outL, out_trans, Wc, bc,
                                            out_pred, out_cls);
}